// Round 10
// baseline (11851.530 us; speedup 1.0000x reference)
//
#include <hip/hip_runtime.h>

#define TT 200
#define BB 128
#define CC 171
#define HH 1024

typedef __attribute__((ext_vector_type(8))) short short8;
typedef __attribute__((ext_vector_type(4))) float f32x4;

__device__ __forceinline__ unsigned short f2bf(float f) {
  unsigned int u = __float_as_uint(f);
  u += 0x7fff + ((u >> 16) & 1);   // RNE
  return (unsigned short)(u >> 16);
}
__device__ __forceinline__ float sigmoidf_(float x) { return 1.f / (1.f + __expf(-x)); }

// coherent (cross-XCD) 16B load: bypass L1+L2, served at Infinity Cache
__device__ __forceinline__ int4 ld_coh16(const void* p) {
  int4 r;
  asm volatile("global_load_dwordx4 %0, %1, off sc0 sc1" : "=v"(r) : "v"(p));
  return r;
}
// coherent 2B store (write-through to IF$)
__device__ __forceinline__ void st_coh2(void* p, unsigned int v) {
  asm volatile("global_store_short %0, %1, off sc0 sc1" :: "v"(p), "v"(v) : "memory");
}
__device__ __forceinline__ void drain_vm() {
  asm volatile("s_waitcnt vmcnt(0)" ::: "memory");
}
__device__ __forceinline__ void waitN4() {   // leave newest 4 vm ops in flight
  asm volatile("s_waitcnt vmcnt(4)" ::: "memory");
}
// WG barrier with LDS-visibility only (no vmcnt drain)
__device__ __forceinline__ void bar_lds() {
  asm volatile("s_waitcnt lgkmcnt(0)" ::: "memory");
  __builtin_amdgcn_s_barrier();
  asm volatile("" ::: "memory");
}

// ---- per-m-group barrier: 64 WGs, monotonic epoch ----
__device__ __forceinline__ void groupbar(int* B, int tid, int epoch) {
  __builtin_amdgcn_s_barrier();    // callers drained stores (waitN4/drain) per-wave already
  if (tid == 0) {
    if (__hip_atomic_fetch_add(&B[0], 1, __ATOMIC_RELAXED, __HIP_MEMORY_SCOPE_AGENT) == epoch * 64 - 1)
      __hip_atomic_store(&B[32], epoch, __ATOMIC_RELAXED, __HIP_MEMORY_SCOPE_AGENT);
    while (__hip_atomic_load(&B[32], __ATOMIC_RELAXED, __HIP_MEMORY_SCOPE_AGENT) < epoch)
      __builtin_amdgcn_s_sleep(1);
  }
  asm volatile("" ::: "memory");
  __builtin_amdgcn_s_barrier();
  asm volatile("" ::: "memory");
}

struct Pre4 { int4 v[4]; };
struct Pre5 { int4 v[5]; };

// ---- geometry (8 waves, M=16, N=64, K-split 4) ----
// grp = wave>>1 (K-group), gw = wave&1 (gate-pair)
// stage: srow = gw*8 + (lane>>3), cj = lane&7
// mfma:  fl = lane&15, fh = lane>>4

// prefetch old-half (stable h): grp's 4 old kt
__device__ __forceinline__ void prefetch_old(const unsigned short* A2, int m0,
                                             int grp, int srow, int cj, Pre4& P) {
  const unsigned short* base = A2 + (size_t)(m0 + srow) * HH + ((cj ^ (srow & 7)) << 3);
#pragma unroll
  for (int j = 0; j < 4; ++j)
    P.v[j] = ld_coh16(base + (grp * 4 + j) * 64);
}

// prefetch gt-L1 A (seq f32->bf16 + old h1); ends fully drained
__device__ __forceinline__ void prefetch_gtl1(const float* seqt, const unsigned short* H1old,
                                              int m0, int grp, int srow, int cj, Pre5& P) {
  const int kt0 = grp * 5;
  const int ktn = 4 + (grp < 3 ? 1 : 0);
  const float* srowp = seqt + (size_t)(m0 + srow) * (TT * CC);
  const unsigned short* hbase = H1old + (size_t)(m0 + srow) * HH + ((cj ^ (srow & 7)) << 3);
#pragma unroll
  for (int i = 0; i < 5; ++i) {
    if (i < ktn) {
      int kt = kt0 + i;
      if (kt < 3) {
        int c0 = kt * 64 + ((cj ^ (srow & 7)) << 3);
        unsigned int w[4];
#pragma unroll
        for (int jj = 0; jj < 4; ++jj) {
          int ca = c0 + 2 * jj, cb = c0 + 2 * jj + 1;
          float va = (ca < CC) ? srowp[ca] : 0.f;
          float vb = (cb < CC) ? srowp[cb] : 0.f;
          w[jj] = (unsigned int)f2bf(va) | ((unsigned int)f2bf(vb) << 16);
        }
        P.v[i] = make_int4(w[0], w[1], w[2], w[3]);
      } else {
        P.v[i] = ld_coh16(hbase + (kt - 3) * 64);
      }
    }
  }
  drain_vm();
}

// epilogue: K-partial exchange (4 grps) + LSTM cell + coherent h-store
__device__ __forceinline__ void exchange_cell(f32x4 acc0, f32x4 acc1,
    const float* bias, float& creg, unsigned short* Hout,
    char* smem, int m0, int n0, int ntile, int tid) {
  const int wave = tid >> 6, lane = tid & 63;
  const int grp = wave >> 1, gw = wave & 1;
  const int fl = lane & 15, fh = lane >> 4;
  bar_lds();                                   // MFMA LDS reads done before ex overlays A
  float* ex = (float*)smem;                    // [grp4][gate4][row16][col16]
#pragma unroll
  for (int r = 0; r < 4; ++r) {
    ex[((grp * 4 + gw * 2 + 0) * 16 + fh * 4 + r) * 16 + fl] = acc0[r];
    ex[((grp * 4 + gw * 2 + 1) * 16 + fh * 4 + r) * 16 + fl] = acc1[r];
  }
  bar_lds();
  if (tid < 256) {
    int urow = tid >> 4, uu = tid & 15;
    float g4[4];
#pragma unroll
    for (int gg = 0; gg < 4; ++gg) {
      float s = ex[((0 + gg) * 16 + urow) * 16 + uu] + ex[((4 + gg) * 16 + urow) * 16 + uu]
              + ex[((8 + gg) * 16 + urow) * 16 + uu] + ex[((12 + gg) * 16 + urow) * 16 + uu];
      g4[gg] = s + bias[n0 + gg * 16 + uu];
    }
    float cn = sigmoidf_(g4[1]) * creg + sigmoidf_(g4[0]) * tanhf(g4[2]);
    creg = cn;
    st_coh2(Hout + (size_t)(m0 + urow) * HH + ntile * 16 + uu,
            (unsigned int)f2bf(sigmoidf_(g4[3]) * tanhf(cn)));
  }
}

// split phase: 16 new kt (A1, loaded here) + 16 old kt (prefetched P). Slots 2KB.
__device__ __forceinline__ void lstm_split(
    const unsigned short* __restrict__ A1,
    const unsigned short* __restrict__ Wa, int sWa,
    const unsigned short* __restrict__ Wb, int sWb,
    const float* __restrict__ bias,
    float& creg, unsigned short* __restrict__ Hout,
    char* smem, int m0, int n0, int ntile, int tid, const Pre4& P)
{
  const int wave = tid >> 6, lane = tid & 63;
  const int grp = wave >> 1, gw = wave & 1;
  const int srow = gw * 8 + (lane >> 3), cj = lane & 7;
  const int fl = lane & 15, fh = lane >> 4;
  const int swz = (fl & 7) << 4;
  char* G = smem + grp * 16384;

  int4 anew[4];
  const unsigned short* nb = A1 + (size_t)(m0 + srow) * HH + ((cj ^ (srow & 7)) << 3);
#pragma unroll
  for (int j = 0; j < 4; ++j)
    anew[j] = ld_coh16(nb + (grp * 4 + j) * 64);
  waitN4();                                    // old prefetch landed; anew in flight
#pragma unroll
  for (int j = 0; j < 4; ++j)
    *(int4*)(G + (4 + j) * 2048 + srow * 128 + cj * 16) = P.v[j];
  bar_lds();

  f32x4 acc0 = {0.f, 0.f, 0.f, 0.f}, acc1 = {0.f, 0.f, 0.f, 0.f};
  const unsigned short* wb0 = Wb + (size_t)(n0 + gw * 32 + fl) * sWb + fh * 8;
  const unsigned short* wb1 = wb0 + 16 * sWb;
#pragma unroll
  for (int j = 0; j < 4; ++j) {                // old half (hides anew latency)
#pragma unroll
    for (int kk = 0; kk < 2; ++kk) {
      short8 b0 = *(const short8*)(wb0 + (grp * 4 + j) * 64 + kk * 32);
      short8 b1 = *(const short8*)(wb1 + (grp * 4 + j) * 64 + kk * 32);
      short8 a = *(const short8*)(G + (4 + j) * 2048 + fl * 128 + ((kk * 64 + fh * 16) ^ swz));
      acc0 = __builtin_amdgcn_mfma_f32_16x16x32_bf16(a, b0, acc0, 0, 0, 0);
      acc1 = __builtin_amdgcn_mfma_f32_16x16x32_bf16(a, b1, acc1, 0, 0, 0);
    }
  }
  drain_vm();
#pragma unroll
  for (int j = 0; j < 4; ++j)
    *(int4*)(G + j * 2048 + srow * 128 + cj * 16) = anew[j];
  bar_lds();
  const unsigned short* wa0 = Wa + (size_t)(n0 + gw * 32 + fl) * sWa + fh * 8;
  const unsigned short* wa1 = wa0 + 16 * sWa;
#pragma unroll
  for (int j = 0; j < 4; ++j) {                // new half
#pragma unroll
    for (int kk = 0; kk < 2; ++kk) {
      short8 b0 = *(const short8*)(wa0 + (grp * 4 + j) * 64 + kk * 32);
      short8 b1 = *(const short8*)(wa1 + (grp * 4 + j) * 64 + kk * 32);
      short8 a = *(const short8*)(G + j * 2048 + fl * 128 + ((kk * 64 + fh * 16) ^ swz));
      acc0 = __builtin_amdgcn_mfma_f32_16x16x32_bf16(a, b0, acc0, 0, 0, 0);
      acc1 = __builtin_amdgcn_mfma_f32_16x16x32_bf16(a, b1, acc1, 0, 0, 0);
    }
  }
  exchange_cell(acc0, acc1, bias, creg, Hout, smem, m0, n0, ntile, tid);
}

// gt-step L1: K=19 kt fully prefetched (seq + old h1)
__device__ __forceinline__ void lstm_gtl1(const Pre5& P,
    const unsigned short* __restrict__ Wih1p, const unsigned short* __restrict__ Whh1,
    const float* __restrict__ bias,
    float& creg, unsigned short* __restrict__ Hout,
    char* smem, int m0, int n0, int ntile, int tid)
{
  const int wave = tid >> 6, lane = tid & 63;
  const int grp = wave >> 1, gw = wave & 1;
  const int srow = gw * 8 + (lane >> 3), cj = lane & 7;
  const int fl = lane & 15, fh = lane >> 4;
  const int swz = (fl & 7) << 4;
  const int kt0 = grp * 5;
  const int ktn = 4 + (grp < 3 ? 1 : 0);
  char* G = smem + grp * 16384;

#pragma unroll
  for (int i = 0; i < 5; ++i)
    if (i < ktn) *(int4*)(G + i * 2048 + srow * 128 + cj * 16) = P.v[i];
  bar_lds();

  f32x4 acc0 = {0.f, 0.f, 0.f, 0.f}, acc1 = {0.f, 0.f, 0.f, 0.f};
#pragma unroll
  for (int i = 0; i < 5; ++i) {
    if (i < ktn) {
      int kt = kt0 + i;
      int sW = (kt < 3) ? 192 : HH;
      const unsigned short* wr0 = ((kt < 3)
          ? Wih1p + (size_t)(n0 + gw * 32 + fl) * 192 + kt * 64
          : Whh1 + (size_t)(n0 + gw * 32 + fl) * HH + (kt - 3) * 64) + fh * 8;
      const unsigned short* wr1 = wr0 + 16 * sW;
#pragma unroll
      for (int kk = 0; kk < 2; ++kk) {
        short8 b0 = *(const short8*)(wr0 + kk * 32);
        short8 b1 = *(const short8*)(wr1 + kk * 32);
        short8 a = *(const short8*)(G + i * 2048 + fl * 128 + ((kk * 64 + fh * 16) ^ swz));
        acc0 = __builtin_amdgcn_mfma_f32_16x16x32_bf16(a, b0, acc0, 0, 0, 0);
        acc1 = __builtin_amdgcn_mfma_f32_16x16x32_bf16(a, b1, acc1, 0, 0, 0);
      }
    }
  }
  exchange_cell(acc0, acc1, bias, creg, Hout, smem, m0, n0, ntile, tid);
}

// ---- decoder (self-contained): 11 WGs per m-group, 16 rows x 16 cols, K=1024 over 8 waves ----
__device__ __forceinline__ void dec_exec(const unsigned short* __restrict__ H3in,
    const unsigned short* __restrict__ Wd, const float* __restrict__ bd,
    float* __restrict__ out, int t, char* smem, int dd, int tid, int m0)
{
  const int wave = tid >> 6, lane = tid & 63;
  const int cj = lane & 7;
  const int fl = lane & 15, fh = lane >> 4;
  const int swz = (fl & 7) << 4;
  int4 P[4];
#pragma unroll
  for (int q = 0; q < 4; ++q) {
    int k = q >> 1, s = q & 1;
    int row = s * 8 + (lane >> 3);
    P[q] = ld_coh16(H3in + (size_t)(m0 + row) * HH + wave * 128 + k * 64 + ((cj ^ (row & 7)) << 3));
  }
  drain_vm();
  char* Dr = smem + 16384 + wave * 4096;
#pragma unroll
  for (int q = 0; q < 4; ++q) {
    int k = q >> 1, s = q & 1;
    int row = s * 8 + (lane >> 3);
    *(int4*)(Dr + k * 2048 + row * 128 + cj * 16) = P[q];
  }
  bar_lds();
  f32x4 acc = {0.f, 0.f, 0.f, 0.f};
  const unsigned short* wr = Wd + (size_t)(dd * 16 + fl) * HH + wave * 128 + fh * 8;
#pragma unroll
  for (int k = 0; k < 2; ++k) {
#pragma unroll
    for (int kk = 0; kk < 2; ++kk) {
      short8 b0 = *(const short8*)(wr + k * 64 + kk * 32);
      short8 a = *(const short8*)(Dr + k * 2048 + fl * 128 + ((kk * 64 + fh * 16) ^ swz));
      acc = __builtin_amdgcn_mfma_f32_16x16x32_bf16(a, b0, acc, 0, 0, 0);
    }
  }
  bar_lds();                                   // prior ex reads done; pex overlays smem+0
  float* pex = (float*)smem;                   // [wave8][row16][col16]
#pragma unroll
  for (int r = 0; r < 4; ++r)
    pex[(wave * 16 + fh * 4 + r) * 16 + fl] = acc[r];
  bar_lds();
  if (tid < 256) {
    int rrow = tid >> 4, uu = tid & 15;
    int c = dd * 16 + uu;
    if (c < CC) {
      float s = 0.f;
#pragma unroll
      for (int v = 0; v < 8; ++v) s += pex[(v * 16 + rrow) * 16 + uu];
      out[(size_t)(m0 + rrow) * (TT * CC) + (size_t)t * CC + c] = s + bd[c];
    }
  }
}

// ---------------- persistent megakernel: 512 WGs x 512 threads, 2 WGs/CU ----------------
__global__ __launch_bounds__(512, 4) void persistent_lstm(
    const unsigned short* __restrict__ Wih1p, const unsigned short* __restrict__ Whh1,
    const unsigned short* __restrict__ Wf, const unsigned short* __restrict__ W2,
    const unsigned short* __restrict__ W3, const unsigned short* __restrict__ Wd,
    const float* __restrict__ B1gt, const float* __restrict__ B1sc,
    const float* __restrict__ B2, const float* __restrict__ B3, const float* __restrict__ Bd,
    unsigned short* __restrict__ Hb, const float* __restrict__ seq, float* __restrict__ out,
    const int* __restrict__ gtp, const int* __restrict__ condp, int* __restrict__ bar)
{
  __shared__ char smem[65536];
  const int wg = blockIdx.x, tid = threadIdx.x;
  const int w8 = wg & 255, half = wg >> 8;
  const int xg = w8 & 7, sl = w8 >> 3;
  const int mgrp = (sl & 3) + half * 4;        // CU's two WGs land in different m-groups
  const int m0 = mgrp * 16;
  const int ntile = xg * 8 + (sl >> 2);        // same ntile for both WGs of a CU (L2 reuse)
  const int n0 = ntile * 64;
  const int gt = *gtp, cond = *condp;
  const int per = gt + cond;
  const int lane = tid & 63, wave = tid >> 6;
  const int grp = wave >> 1, gw = wave & 1;
  const int srow = gw * 8 + (lane >> 3), cj = lane & 7;

  int dd = ((ntile & 7) << 3) | (ntile >> 3);  // bit-swap: dec WGs spread over XCDs
  const int decid = (dd < 11) ? dd : -1;

  unsigned short* H1[2] = { Hb + 0 * BB * HH, Hb + 1 * BB * HH };
  unsigned short* H2[2] = { Hb + 2 * BB * HH, Hb + 3 * BB * HH };
  unsigned short* H3[2] = { Hb + 4 * BB * HH, Hb + 5 * BB * HH };
  int* B = bar + mgrp * 64;

  float c1 = 0.f, c2 = 0.f, c3 = 0.f;
  Pre4 aold; Pre5 a1pre;
  int e = 0, tm = 0;
  bool gts = (per > 0) ? (0 < gt) : true;
  if (gts) prefetch_gtl1(seq, H1[0], m0, grp, srow, cj, a1pre);
  else   { prefetch_old(H1[0], m0, grp, srow, cj, aold); waitN4(); }

  for (int t = 0; t < TT; ++t) {
    int p = t & 1;
    // ---- L1 ----
    if (gts) lstm_gtl1(a1pre, Wih1p, Whh1, B1gt, c1, H1[1 - p], smem, m0, n0, ntile, tid);
    else     lstm_split(H3[p], Wf, HH, Whh1, HH, B1sc, c1, H1[1 - p],
                        smem, m0, n0, ntile, tid, aold);
    if (decid >= 0 && t > 0) dec_exec(H3[p], Wd, Bd, out, t - 1, smem, decid, tid, m0);
    prefetch_old(H2[p], m0, grp, srow, cj, aold);
    waitN4();
    groupbar(B, tid, ++e);
    // ---- L2 ----
    lstm_split(H1[1 - p], W2, 2048, W2 + 1024, 2048, B2, c2, H2[1 - p],
               smem, m0, n0, ntile, tid, aold);
    prefetch_old(H3[p], m0, grp, srow, cj, aold);
    waitN4();
    groupbar(B, tid, ++e);
    // ---- L3 ----
    lstm_split(H2[1 - p], W3, 2048, W3 + 1024, 2048, B3, c3, H3[1 - p],
               smem, m0, n0, ntile, tid, aold);
    int tmn = (tm + 1 == per) ? 0 : tm + 1;
    bool gtsn = (per > 0) ? (tmn < gt) : true;
    if (t + 1 < TT) {
      if (gtsn) prefetch_gtl1(seq + (size_t)(t + 1) * CC, H1[1 - p], m0, grp, srow, cj, a1pre);
      else { prefetch_old(H1[1 - p], m0, grp, srow, cj, aold); waitN4(); }
    } else drain_vm();
    groupbar(B, tid, ++e);
    tm = tmn; gts = gtsn;
  }
  if (decid >= 0)                              // out[:, 199, :] from h3(199) in H3[0]
    dec_exec(H3[0], Wd, Bd, out, TT - 1, smem, decid, tid, m0);
}

// ---------------- conversion / init kernels ----------------
__device__ __forceinline__ int perm_orig_row(int np) {
  return ((np >> 4) & 3) * HH + ((np >> 6) << 4) + (np & 15);
}

__global__ void conv_wih1p(const float* __restrict__ Wih, unsigned short* __restrict__ dst) {
  int np = blockIdx.x, k = threadIdx.x;          // block 192
  int n = perm_orig_row(np);
  dst[(size_t)np * 192 + k] = f2bf((k < CC) ? Wih[(size_t)n * CC + k] : 0.f);
}

__global__ void conv_whh1(const float* __restrict__ Whh, unsigned short* __restrict__ dst) {
  int np = blockIdx.y, k = blockIdx.x * 256 + threadIdx.x;   // grid (4, 4096)
  int n = perm_orig_row(np);
  dst[(size_t)np * HH + k] = f2bf(Whh[(size_t)n * HH + k]);
}

__global__ void conv_w23(const float* __restrict__ Wih, const float* __restrict__ Whh,
                         unsigned short* __restrict__ dst) {
  int k = blockIdx.x * 256 + threadIdx.x;        // grid (8, 4096)
  int np = blockIdx.y;
  int n = perm_orig_row(np);
  float v = (k < HH) ? Wih[(size_t)n * HH + k] : Whh[(size_t)n * HH + (k - HH)];
  dst[(size_t)np * 2048 + k] = f2bf(v);
}

__global__ void conv_wd(const float* __restrict__ Wsrc, unsigned short* __restrict__ dst) {
  int k = blockIdx.x * 256 + threadIdx.x;        // grid (4, 176)
  int row = blockIdx.y;
  dst[(size_t)row * HH + k] = f2bf((row < CC) ? Wsrc[(size_t)row * HH + k] : 0.f);
}

__global__ void wf_gemm(const float* __restrict__ Wih1, const float* __restrict__ Wdec,
                        unsigned short* __restrict__ Wfo) {
  int j = blockIdx.x * 256 + threadIdx.x;        // grid (4, 4096)
  int np = blockIdx.y;
  int n = perm_orig_row(np);
  const float* wr = Wih1 + (size_t)n * CC;
  float acc = 0.f;
  for (int c = 0; c < CC; ++c) acc = fmaf(wr[c], Wdec[(size_t)c * HH + j], acc);
  Wfo[(size_t)np * HH + j] = f2bf(acc);
}

__global__ void bias_all(const float* bi1, const float* bh1, const float* Wih1, const float* bdec,
                         const float* bi2, const float* bh2, const float* bi3, const float* bh3,
                         float* o1gt, float* o1sc, float* o2, float* o3, float* od) {
  int idx = blockIdx.x * 256 + threadIdx.x;
  if (idx < 4096) {
    int n = perm_orig_row(idx);
    float b = bi1[n] + bh1[n];
    o1gt[idx] = b;
    const float* wr = Wih1 + (size_t)n * CC;
    float acc = 0.f;
    for (int c = 0; c < CC; ++c) acc = fmaf(wr[c], bdec[c], acc);
    o1sc[idx] = b + acc;
  } else if (idx < 8192) {
    int np = idx - 4096; int n = perm_orig_row(np);
    o2[np] = bi2[n] + bh2[n];
  } else if (idx < 12288) {
    int np = idx - 8192; int n = perm_orig_row(np);
    o3[np] = bi3[n] + bh3[n];
  } else if (idx < 12464) {
    int c2 = idx - 12288;
    od[c2] = (c2 < CC) ? bdec[c2] : 0.f;
  }
}

__global__ void init_state(unsigned short* __restrict__ Hall, int* __restrict__ bar) {
  int idx = blockIdx.x * blockDim.x + threadIdx.x;   // grid 3072 x 256
  if (idx < 6 * BB * HH) Hall[idx] = 0;
  if (idx < 1024) bar[idx] = 0;
}

extern "C" void kernel_launch(void* const* d_in, const int* in_sizes, int n_in,
                              void* d_out, int out_size, void* d_ws, size_t ws_size,
                              hipStream_t stream)
{
  const float* seq   = (const float*)d_in[0];
  const float* W_ih1 = (const float*)d_in[1];
  const float* W_hh1 = (const float*)d_in[2];
  const float* b_ih1 = (const float*)d_in[3];
  const float* b_hh1 = (const float*)d_in[4];
  const float* W_ih2 = (const float*)d_in[5];
  const float* W_hh2 = (const float*)d_in[6];
  const float* b_ih2 = (const float*)d_in[7];
  const float* b_hh2 = (const float*)d_in[8];
  const float* W_ih3 = (const float*)d_in[9];
  const float* W_hh3 = (const float*)d_in[10];
  const float* b_ih3 = (const float*)d_in[11];
  const float* b_hh3 = (const float*)d_in[12];
  const float* W_dec = (const float*)d_in[13];
  const float* b_dec = (const float*)d_in[14];
  const int* condp   = (const int*)d_in[15];
  const int* gtp     = (const int*)d_in[16];
  float* out = (float*)d_out;
  char* ws = (char*)d_ws;

  if (ws_size < 53908480) return;

  unsigned short* Wih1p = (unsigned short*)(ws + 0);
  unsigned short* Whh1  = (unsigned short*)(ws + 1572864);
  unsigned short* Wf    = (unsigned short*)(ws + 9961472);
  unsigned short* W2    = (unsigned short*)(ws + 18350080);
  unsigned short* W3    = (unsigned short*)(ws + 35127296);
  unsigned short* Wd    = (unsigned short*)(ws + 51904512);
  float* B1gt = (float*)(ws + 52264960);
  float* B1sc = (float*)(ws + 52281344);
  float* B2   = (float*)(ws + 52297728);
  float* B3   = (float*)(ws + 52314112);
  float* Bd   = (float*)(ws + 52330496);
  unsigned short* Hbase = (unsigned short*)(ws + 52331520);
  int* bar = (int*)(ws + 53904384);

  conv_wih1p<<<dim3(4096),    192, 0, stream>>>(W_ih1, Wih1p);
  conv_whh1 <<<dim3(4, 4096), 256, 0, stream>>>(W_hh1, Whh1);
  wf_gemm   <<<dim3(4, 4096), 256, 0, stream>>>(W_ih1, W_dec, Wf);
  conv_w23  <<<dim3(8, 4096), 256, 0, stream>>>(W_ih2, W_hh2, W2);
  conv_w23  <<<dim3(8, 4096), 256, 0, stream>>>(W_ih3, W_hh3, W3);
  conv_wd   <<<dim3(4, 176),  256, 0, stream>>>(W_dec, Wd);
  bias_all  <<<dim3(49),      256, 0, stream>>>(b_ih1, b_hh1, W_ih1, b_dec,
                                                b_ih2, b_hh2, b_ih3, b_hh3,
                                                B1gt, B1sc, B2, B3, Bd);
  init_state<<<dim3(3072),    256, 0, stream>>>(Hbase, bar);

  persistent_lstm<<<dim3(512), dim3(512), 0, stream>>>(
      Wih1p, Whh1, Wf, W2, W3, Wd, B1gt, B1sc, B2, B3, Bd,
      Hbase, seq, out, gtp, condp, bar);
}

// Round 11
// 6761.039 us; speedup vs baseline: 1.7529x; 1.7529x over previous
//
#include <hip/hip_runtime.h>

#define TT 200
#define BB 128
#define CC 171
#define HH 1024

typedef __attribute__((ext_vector_type(8))) short short8;
typedef __attribute__((ext_vector_type(4))) float f32x4;

__device__ __forceinline__ unsigned short f2bf(float f) {
  unsigned int u = __float_as_uint(f);
  u += 0x7fff + ((u >> 16) & 1);   // RNE
  return (unsigned short)(u >> 16);
}
__device__ __forceinline__ float sigmoidf_(float x) { return 1.f / (1.f + __expf(-x)); }

// coherent (cross-XCD) 16B load: bypass L1+L2, served at Infinity Cache
__device__ __forceinline__ int4 ld_coh16(const void* p) {
  int4 r;
  asm volatile("global_load_dwordx4 %0, %1, off sc0 sc1" : "=v"(r) : "v"(p));
  return r;
}
// coherent 2B store (write-through to IF$)
__device__ __forceinline__ void st_coh2(void* p, unsigned int v) {
  asm volatile("global_store_short %0, %1, off sc0 sc1" :: "v"(p), "v"(v) : "memory");
}
__device__ __forceinline__ void drain_vm() {
  asm volatile("s_waitcnt vmcnt(0)" ::: "memory");
}
__device__ __forceinline__ void waitN4() {   // leave newest 4 vm ops in flight
  asm volatile("s_waitcnt vmcnt(4)" ::: "memory");
}
// WG barrier with LDS-visibility only (no vmcnt drain)
__device__ __forceinline__ void bar_lds() {
  asm volatile("s_waitcnt lgkmcnt(0)" ::: "memory");
  __builtin_amdgcn_s_barrier();
  asm volatile("" ::: "memory");
}

// ---- per-m-group barrier: 64 WGs, direct monotonic-counter poll ----
__device__ __forceinline__ void groupbar(int* B, int tid, int epoch) {
  __builtin_amdgcn_s_barrier();    // callers drained their stores (waitN4/drain) per-wave
  if (tid == 0) {
    __hip_atomic_fetch_add(&B[0], 1, __ATOMIC_RELAXED, __HIP_MEMORY_SCOPE_AGENT);
    while (__hip_atomic_load(&B[0], __ATOMIC_RELAXED, __HIP_MEMORY_SCOPE_AGENT) < epoch * 64)
      __builtin_amdgcn_s_sleep(1);
  }
  asm volatile("" ::: "memory");
  __builtin_amdgcn_s_barrier();
  asm volatile("" ::: "memory");
}

struct Pre4 { int4 v[4]; };
struct Pre5 { int4 v[5]; };

// ---- geometry (16 waves, M=32, N=64, K-split 4) ----
// grp = wave>>2, gw = wave&3; stage row = gw*8 + (lane>>3), lj = lane&7
// mfma: fl = lane&15, fh = lane>>4

// prefetch old-half (stable h): grp's 4 old kt
__device__ __forceinline__ void prefetch_old(const unsigned short* A2, int m0,
                                             int grp, int row, int lj, Pre4& P) {
  const unsigned short* base = A2 + (size_t)(m0 + row) * HH + ((lj ^ (row & 7)) << 3);
#pragma unroll
  for (int j = 0; j < 4; ++j)
    P.v[j] = ld_coh16(base + (grp * 4 + j) * 64);
}

// prefetch gt-L1 A (seq f32->bf16 + old h1); ends fully drained
__device__ __forceinline__ void prefetch_gtl1(const float* seqt, const unsigned short* H1old,
                                              int m0, int grp, int row, int lj, Pre5& P) {
  const int kt0 = grp * 5;
  const int ktn = 4 + (grp < 3 ? 1 : 0);
  const float* srow = seqt + (size_t)(m0 + row) * (TT * CC);
  const unsigned short* hbase = H1old + (size_t)(m0 + row) * HH + ((lj ^ (row & 7)) << 3);
#pragma unroll
  for (int i = 0; i < 5; ++i) {
    if (i < ktn) {
      int kt = kt0 + i;
      if (kt < 3) {
        int c0 = kt * 64 + ((lj ^ (row & 7)) << 3);
        unsigned int w[4];
#pragma unroll
        for (int jj = 0; jj < 4; ++jj) {
          int ca = c0 + 2 * jj, cb = c0 + 2 * jj + 1;
          float va = (ca < CC) ? srow[ca] : 0.f;
          float vb = (cb < CC) ? srow[cb] : 0.f;
          w[jj] = (unsigned int)f2bf(va) | ((unsigned int)f2bf(vb) << 16);
        }
        P.v[i] = make_int4(w[0], w[1], w[2], w[3]);
      } else {
        P.v[i] = ld_coh16(hbase + (kt - 3) * 64);
      }
    }
  }
  drain_vm();
}

// epilogue: K-partial exchange + LSTM cell + coherent h-store
__device__ __forceinline__ void exchange_cell(f32x4 acc0, f32x4 acc1,
    const float* bias, float& creg, unsigned short* Hout,
    char* smem, int m0, int n0, int ntile, int tid) {
  const int wave = tid >> 6, lane = tid & 63;
  const int grp = wave >> 2, gw = wave & 3;
  const int fl = lane & 15, fh = lane >> 4;
  bar_lds();                                   // MFMA LDS reads done before ex overlays A
  float* ex = (float*)smem;
#pragma unroll
  for (int r = 0; r < 4; ++r) {
    ex[((grp * 4 + gw) * 32 + fh * 4 + r) * 16 + fl] = acc0[r];
    ex[((grp * 4 + gw) * 32 + 16 + fh * 4 + r) * 16 + fl] = acc1[r];
  }
  bar_lds();
  if (tid < 512) {
    int urow = tid >> 4, uu = tid & 15;
    float g4[4];
#pragma unroll
    for (int gg = 0; gg < 4; ++gg) {
      float s = ex[((0 + gg) * 32 + urow) * 16 + uu] + ex[((4 + gg) * 32 + urow) * 16 + uu]
              + ex[((8 + gg) * 32 + urow) * 16 + uu] + ex[((12 + gg) * 32 + urow) * 16 + uu];
      g4[gg] = s + bias[n0 + gg * 16 + uu];
    }
    float cn = sigmoidf_(g4[1]) * creg + sigmoidf_(g4[0]) * tanhf(g4[2]);
    creg = cn;
    st_coh2(Hout + (size_t)(m0 + urow) * HH + ntile * 16 + uu,
            (unsigned int)f2bf(sigmoidf_(g4[3]) * tanhf(cn)));
  }
}

// split phase: 16 new kt (A1, loaded here) + 16 old kt (prefetched P). Slots 4KB.
__device__ __forceinline__ void lstm_split(
    const unsigned short* __restrict__ A1,
    const unsigned short* __restrict__ Wa, int sWa,
    const unsigned short* __restrict__ Wb, int sWb,
    const float* __restrict__ bias,
    float& creg, unsigned short* __restrict__ Hout,
    char* smem, int m0, int n0, int ntile, int tid, const Pre4& P)
{
  const int wave = tid >> 6, lane = tid & 63;
  const int grp = wave >> 2, gw = wave & 3;
  const int lrow = lane >> 3, lj = lane & 7;
  const int fl = lane & 15, fh = lane >> 4;
  const int row = gw * 8 + lrow;
  const int swz = (fl & 7) << 4;
  char* G = smem + grp * 32768;

  int4 anew[4];
  const unsigned short* nb = A1 + (size_t)(m0 + row) * HH + ((lj ^ (row & 7)) << 3);
#pragma unroll
  for (int j = 0; j < 4; ++j)
    anew[j] = ld_coh16(nb + (grp * 4 + j) * 64);
  waitN4();                                    // old prefetch landed; anew in flight
#pragma unroll
  for (int j = 0; j < 4; ++j)
    *(int4*)(G + (4 + j) * 4096 + row * 128 + lj * 16) = P.v[j];
  bar_lds();

  f32x4 acc0 = {0.f, 0.f, 0.f, 0.f}, acc1 = {0.f, 0.f, 0.f, 0.f};
  const unsigned short* wbr = Wb + (size_t)(n0 + gw * 16 + fl) * sWb + fh * 8;
#pragma unroll
  for (int j = 0; j < 4; ++j) {                // old half (hides anew latency)
#pragma unroll
    for (int kk = 0; kk < 2; ++kk) {
      short8 b0 = *(const short8*)(wbr + (grp * 4 + j) * 64 + kk * 32);
      int colb = kk * 64 + fh * 16;
      short8 a0 = *(const short8*)(G + (4 + j) * 4096 + fl * 128 + (colb ^ swz));
      short8 a1 = *(const short8*)(G + (4 + j) * 4096 + (16 + fl) * 128 + (colb ^ swz));
      acc0 = __builtin_amdgcn_mfma_f32_16x16x32_bf16(a0, b0, acc0, 0, 0, 0);
      acc1 = __builtin_amdgcn_mfma_f32_16x16x32_bf16(a1, b0, acc1, 0, 0, 0);
    }
  }
  drain_vm();
#pragma unroll
  for (int j = 0; j < 4; ++j)
    *(int4*)(G + j * 4096 + row * 128 + lj * 16) = anew[j];
  bar_lds();
  const unsigned short* war = Wa + (size_t)(n0 + gw * 16 + fl) * sWa + fh * 8;
#pragma unroll
  for (int j = 0; j < 4; ++j) {                // new half
#pragma unroll
    for (int kk = 0; kk < 2; ++kk) {
      short8 b0 = *(const short8*)(war + (grp * 4 + j) * 64 + kk * 32);
      int colb = kk * 64 + fh * 16;
      short8 a0 = *(const short8*)(G + j * 4096 + fl * 128 + (colb ^ swz));
      short8 a1 = *(const short8*)(G + j * 4096 + (16 + fl) * 128 + (colb ^ swz));
      acc0 = __builtin_amdgcn_mfma_f32_16x16x32_bf16(a0, b0, acc0, 0, 0, 0);
      acc1 = __builtin_amdgcn_mfma_f32_16x16x32_bf16(a1, b0, acc1, 0, 0, 0);
    }
  }
  exchange_cell(acc0, acc1, bias, creg, Hout, smem, m0, n0, ntile, tid);
}

// gt-step L1: K=19 kt fully prefetched (seq + old h1)
__device__ __forceinline__ void lstm_gtl1(const Pre5& P,
    const unsigned short* __restrict__ Wih1p, const unsigned short* __restrict__ Whh1,
    const float* __restrict__ bias,
    float& creg, unsigned short* __restrict__ Hout,
    char* smem, int m0, int n0, int ntile, int tid)
{
  const int wave = tid >> 6, lane = tid & 63;
  const int grp = wave >> 2, gw = wave & 3;
  const int lrow = lane >> 3, lj = lane & 7;
  const int fl = lane & 15, fh = lane >> 4;
  const int row = gw * 8 + lrow;
  const int swz = (fl & 7) << 4;
  const int kt0 = grp * 5;
  const int ktn = 4 + (grp < 3 ? 1 : 0);
  char* G = smem + grp * 32768;

#pragma unroll
  for (int i = 0; i < 5; ++i)
    if (i < ktn) *(int4*)(G + i * 4096 + row * 128 + lj * 16) = P.v[i];
  bar_lds();

  f32x4 acc0 = {0.f, 0.f, 0.f, 0.f}, acc1 = {0.f, 0.f, 0.f, 0.f};
#pragma unroll
  for (int i = 0; i < 5; ++i) {
    if (i < ktn) {
      int kt = kt0 + i;
      const unsigned short* wr = (kt < 3)
          ? Wih1p + (size_t)(n0 + gw * 16 + fl) * 192 + kt * 64 + fh * 8
          : Whh1 + (size_t)(n0 + gw * 16 + fl) * HH + (kt - 3) * 64 + fh * 8;
#pragma unroll
      for (int kk = 0; kk < 2; ++kk) {
        short8 b0 = *(const short8*)(wr + kk * 32);
        int colb = kk * 64 + fh * 16;
        short8 a0 = *(const short8*)(G + i * 4096 + fl * 128 + (colb ^ swz));
        short8 a1 = *(const short8*)(G + i * 4096 + (16 + fl) * 128 + (colb ^ swz));
        acc0 = __builtin_amdgcn_mfma_f32_16x16x32_bf16(a0, b0, acc0, 0, 0, 0);
        acc1 = __builtin_amdgcn_mfma_f32_16x16x32_bf16(a1, b0, acc1, 0, 0, 0);
      }
    }
  }
  exchange_cell(acc0, acc1, bias, creg, Hout, smem, m0, n0, ntile, tid);
}

// decoder out tile: 32 rows x 16 cols, K=1024 split over 16 waves
__device__ __forceinline__ void dec_out(
    const unsigned short* __restrict__ H3in, const unsigned short* __restrict__ Wd,
    const float* __restrict__ bd, float* __restrict__ out,
    int t, char* smem, int d, int tid, int m0)
{
  const int wave = tid >> 6, lane = tid & 63;
  const int lrow = lane >> 3, lj = lane & 7;
  const int fl = lane & 15, fh = lane >> 4;
  const int n0 = d * 16;
  char* Dr = smem + 65536 + wave * 4096;
  int4 r4[4];
#pragma unroll
  for (int j = 0; j < 4; ++j) {
    int row = j * 8 + lrow;
    r4[j] = ld_coh16(H3in + (size_t)(m0 + row) * HH + wave * 64 + ((lj ^ (row & 7)) << 3));
  }
  drain_vm();
#pragma unroll
  for (int j = 0; j < 4; ++j) {
    int row = j * 8 + lrow;
    *(int4*)(Dr + row * 128 + lj * 16) = r4[j];
  }
  bar_lds();
  f32x4 acc0 = {0.f, 0.f, 0.f, 0.f}, acc1 = {0.f, 0.f, 0.f, 0.f};
  const unsigned short* Wrow = Wd + (size_t)(n0 + fl) * HH + wave * 64 + fh * 8;
  const int swz = (fl & 7) << 4;
#pragma unroll
  for (int kk = 0; kk < 2; ++kk) {
    short8 b0 = *(const short8*)(Wrow + kk * 32);
    int colb = kk * 64 + fh * 16;
    short8 a0 = *(const short8*)(Dr + fl * 128 + (colb ^ swz));
    short8 a1 = *(const short8*)(Dr + (16 + fl) * 128 + (colb ^ swz));
    acc0 = __builtin_amdgcn_mfma_f32_16x16x32_bf16(a0, b0, acc0, 0, 0, 0);
    acc1 = __builtin_amdgcn_mfma_f32_16x16x32_bf16(a1, b0, acc1, 0, 0, 0);
  }
  float* pex = (float*)(smem + 32768);
#pragma unroll
  for (int r = 0; r < 4; ++r) {
    pex[(wave * 32 + fh * 4 + r) * 16 + fl] = acc0[r];
    pex[(wave * 32 + 16 + fh * 4 + r) * 16 + fl] = acc1[r];
  }
  bar_lds();
  if (tid < 512) {
    int rrow = tid >> 4, uu = tid & 15;
    int c = n0 + uu;
    if (c < CC) {
      float s = 0.f;
#pragma unroll
      for (int v = 0; v < 16; ++v) s += pex[(v * 32 + rrow) * 16 + uu];
      out[(size_t)(m0 + rrow) * (TT * CC) + (size_t)t * CC + c] = s + bd[c];
    }
  }
  bar_lds();                                   // allow safe LDS reuse by next job
}

// ---------------- persistent megakernel: 256 WGs x 1024 threads ----------------
// HIST: h3 kept per-step in a 201-slot history; decoder runs post-loop (parallel).
// !HIST: round-8 behavior (2-slot ping-pong + in-loop dec on 11 WGs/m-group).
template<bool HIST>
__global__ __launch_bounds__(1024, 1) void persistent_lstm(
    const unsigned short* __restrict__ Wih1p, const unsigned short* __restrict__ Whh1,
    const unsigned short* __restrict__ Wf, const unsigned short* __restrict__ W2,
    const unsigned short* __restrict__ W3, const unsigned short* __restrict__ Wd,
    const float* __restrict__ B1gt, const float* __restrict__ B1sc,
    const float* __restrict__ B2, const float* __restrict__ B3, const float* __restrict__ Bd,
    unsigned short* __restrict__ Hb, unsigned short* __restrict__ H3s,
    const float* __restrict__ seq, float* __restrict__ out,
    const int* __restrict__ gtp, const int* __restrict__ condp, int* __restrict__ bar)
{
  __shared__ char smem[131072];
  const int wg = blockIdx.x, tid = threadIdx.x;
  const int xg = wg & 7, sl = wg >> 3;
  const int ntile = xg * 8 + (sl >> 2);        // 4 WGs sharing a B-panel on same XCD
  const int mgrp = sl & 3;
  const int m0 = mgrp * 32;
  const int n0 = ntile * 64;
  const int gt = *gtp, cond = *condp;
  const int per = gt + cond;
  const int lane = tid & 63, wave = tid >> 6;
  const int grp = wave >> 2, gw = wave & 3;
  const int row = gw * 8 + (lane >> 3), lj = lane & 7;

  int dd = ((ntile & 7) << 3) | (ntile >> 3);  // bit-swap: dec WGs spread over XCDs
  const int decid = (dd < 11) ? dd : -1;

  unsigned short* H1[2] = { Hb + 0 * BB * HH, Hb + 1 * BB * HH };
  unsigned short* H2[2] = { Hb + 2 * BB * HH, Hb + 3 * BB * HH };
  int* B = bar + mgrp * 64;

  float c1 = 0.f, c2 = 0.f, c3 = 0.f;
  Pre4 aold; Pre5 a1pre;
  int e = 0, tm = 0;
  bool gts = (per > 0) ? (0 < gt) : true;
  if (gts) prefetch_gtl1(seq, H1[0], m0, grp, row, lj, a1pre);
  else   { prefetch_old(H3s /*slot 0 zeros? no: h1 old*/, m0, grp, row, lj, aold); waitN4(); }
  // NOTE: sc-at-t=0 only occurs when gt==0; old half is h1(-1)=zeros in H1[0]:
  if (!gts) { prefetch_old(H1[0], m0, grp, row, lj, aold); waitN4(); }

  for (int t = 0; t < TT; ++t) {
    int p = t & 1;
    const unsigned short* h3prev = H3s + (size_t)(HIST ? t : (t & 1)) * (BB * HH);
    unsigned short* h3out = H3s + (size_t)(HIST ? (t + 1) : ((t + 1) & 1)) * (BB * HH);
    // ---- L1 ----
    if (gts) lstm_gtl1(a1pre, Wih1p, Whh1, B1gt, c1, H1[1 - p], smem, m0, n0, ntile, tid);
    else     lstm_split(h3prev, Wf, HH, Whh1, HH, B1sc, c1, H1[1 - p],
                        smem, m0, n0, ntile, tid, aold);
    if (!HIST && decid >= 0 && t > 0)
      dec_out(h3prev, Wd, Bd, out, t - 1, smem, decid, tid, m0);
    prefetch_old(H2[p], m0, grp, row, lj, aold);
    waitN4();
    groupbar(B, tid, ++e);
    // ---- L2 ----
    lstm_split(H1[1 - p], W2, 2048, W2 + 1024, 2048, B2, c2, H2[1 - p],
               smem, m0, n0, ntile, tid, aold);
    prefetch_old(h3prev, m0, grp, row, lj, aold);
    waitN4();
    groupbar(B, tid, ++e);
    // ---- L3 ----
    lstm_split(H2[1 - p], W3, 2048, W3 + 1024, 2048, B3, c3, h3out,
               smem, m0, n0, ntile, tid, aold);
    int tmn = (tm + 1 == per) ? 0 : tm + 1;
    bool gtsn = (per > 0) ? (tmn < gt) : true;
    if (t + 1 < TT) {
      if (gtsn) prefetch_gtl1(seq + (size_t)(t + 1) * CC, H1[1 - p], m0, grp, row, lj, a1pre);
      else { prefetch_old(H1[1 - p], m0, grp, row, lj, aold); waitN4(); }
    } else drain_vm();
    groupbar(B, tid, ++e);
    tm = tmn; gts = gtsn;
  }

  if (HIST) {
    // post-loop decoder: 2200 (t, coltile) jobs per m-group over 64 WGs
    for (int j = ntile; j < TT * 11; j += 64) {
      int t = j / 11, ct = j - t * 11;
      dec_out(H3s + (size_t)(t + 1) * (BB * HH), Wd, Bd, out, t, smem, ct, tid, m0);
    }
  } else if (decid >= 0) {
    dec_out(H3s + (size_t)(TT & 1) * (BB * HH), Wd, Bd, out, TT - 1, smem, decid, tid, m0);
  }
}

// ---------------- conversion / init kernels ----------------
__device__ __forceinline__ int perm_orig_row(int np) {
  return ((np >> 4) & 3) * HH + ((np >> 6) << 4) + (np & 15);
}

__global__ void conv_wih1p(const float* __restrict__ Wih, unsigned short* __restrict__ dst) {
  int np = blockIdx.x, k = threadIdx.x;          // block 192
  int n = perm_orig_row(np);
  dst[(size_t)np * 192 + k] = f2bf((k < CC) ? Wih[(size_t)n * CC + k] : 0.f);
}

__global__ void conv_whh1(const float* __restrict__ Whh, unsigned short* __restrict__ dst) {
  int np = blockIdx.y, k = blockIdx.x * 256 + threadIdx.x;   // grid (4, 4096)
  int n = perm_orig_row(np);
  dst[(size_t)np * HH + k] = f2bf(Whh[(size_t)n * HH + k]);
}

__global__ void conv_w23(const float* __restrict__ Wih, const float* __restrict__ Whh,
                         unsigned short* __restrict__ dst) {
  int k = blockIdx.x * 256 + threadIdx.x;        // grid (8, 4096)
  int np = blockIdx.y;
  int n = perm_orig_row(np);
  float v = (k < HH) ? Wih[(size_t)n * HH + k] : Whh[(size_t)n * HH + (k - HH)];
  dst[(size_t)np * 2048 + k] = f2bf(v);
}

__global__ void conv_wd(const float* __restrict__ Wsrc, unsigned short* __restrict__ dst) {
  int k = blockIdx.x * 256 + threadIdx.x;        // grid (4, 176)
  int row = blockIdx.y;
  dst[(size_t)row * HH + k] = f2bf((row < CC) ? Wsrc[(size_t)row * HH + k] : 0.f);
}

__global__ void wf_gemm(const float* __restrict__ Wih1, const float* __restrict__ Wdec,
                        unsigned short* __restrict__ Wfo) {
  int j = blockIdx.x * 256 + threadIdx.x;        // grid (4, 4096)
  int np = blockIdx.y;
  int n = perm_orig_row(np);
  const float* wr = Wih1 + (size_t)n * CC;
  float acc = 0.f;
  for (int c = 0; c < CC; ++c) acc = fmaf(wr[c], Wdec[(size_t)c * HH + j], acc);
  Wfo[(size_t)np * HH + j] = f2bf(acc);
}

__global__ void bias_all(const float* bi1, const float* bh1, const float* Wih1, const float* bdec,
                         const float* bi2, const float* bh2, const float* bi3, const float* bh3,
                         float* o1gt, float* o1sc, float* o2, float* o3, float* od) {
  int idx = blockIdx.x * 256 + threadIdx.x;
  if (idx < 4096) {
    int n = perm_orig_row(idx);
    float b = bi1[n] + bh1[n];
    o1gt[idx] = b;
    const float* wr = Wih1 + (size_t)n * CC;
    float acc = 0.f;
    for (int c = 0; c < CC; ++c) acc = fmaf(wr[c], bdec[c], acc);
    o1sc[idx] = b + acc;
  } else if (idx < 8192) {
    int np = idx - 4096; int n = perm_orig_row(np);
    o2[np] = bi2[n] + bh2[n];
  } else if (idx < 12288) {
    int np = idx - 8192; int n = perm_orig_row(np);
    o3[np] = bi3[n] + bh3[n];
  } else if (idx < 12464) {
    int c2 = idx - 12288;
    od[c2] = (c2 < CC) ? bdec[c2] : 0.f;
  }
}

__global__ void init_state(unsigned short* __restrict__ Hall, int nelem,
                           int* __restrict__ bar) {
  int idx = blockIdx.x * blockDim.x + threadIdx.x;   // grid 3072 x 256
  if (idx < nelem) Hall[idx] = 0;
  if (idx < 1024) bar[idx] = 0;
}

extern "C" void kernel_launch(void* const* d_in, const int* in_sizes, int n_in,
                              void* d_out, int out_size, void* d_ws, size_t ws_size,
                              hipStream_t stream)
{
  const float* seq   = (const float*)d_in[0];
  const float* W_ih1 = (const float*)d_in[1];
  const float* W_hh1 = (const float*)d_in[2];
  const float* b_ih1 = (const float*)d_in[3];
  const float* b_hh1 = (const float*)d_in[4];
  const float* W_ih2 = (const float*)d_in[5];
  const float* W_hh2 = (const float*)d_in[6];
  const float* b_ih2 = (const float*)d_in[7];
  const float* b_hh2 = (const float*)d_in[8];
  const float* W_ih3 = (const float*)d_in[9];
  const float* W_hh3 = (const float*)d_in[10];
  const float* b_ih3 = (const float*)d_in[11];
  const float* b_hh3 = (const float*)d_in[12];
  const float* W_dec = (const float*)d_in[13];
  const float* b_dec = (const float*)d_in[14];
  const int* condp   = (const int*)d_in[15];
  const int* gtp     = (const int*)d_in[16];
  float* out = (float*)d_out;
  char* ws = (char*)d_ws;

  const size_t SLOT = (size_t)BB * HH * 2;     // 262144 B
  const size_t HBOFF = 52331520;               // after weights+biases
  const size_t H3OFF = HBOFF + 4 * SLOT;       // after H1[2], H2[2]
  const size_t needHist = H3OFF + 201 * SLOT + 4096;   // 106,075,136
  const size_t needPing = H3OFF + 2 * SLOT + 4096;     //  53,908,480
  if (ws_size < needPing) return;
  const bool hist = (ws_size >= needHist);

  unsigned short* Wih1p = (unsigned short*)(ws + 0);
  unsigned short* Whh1  = (unsigned short*)(ws + 1572864);
  unsigned short* Wf    = (unsigned short*)(ws + 9961472);
  unsigned short* W2    = (unsigned short*)(ws + 18350080);
  unsigned short* W3    = (unsigned short*)(ws + 35127296);
  unsigned short* Wd    = (unsigned short*)(ws + 51904512);
  float* B1gt = (float*)(ws + 52264960);
  float* B1sc = (float*)(ws + 52281344);
  float* B2   = (float*)(ws + 52297728);
  float* B3   = (float*)(ws + 52314112);
  float* Bd   = (float*)(ws + 52330496);
  unsigned short* Hb  = (unsigned short*)(ws + HBOFF);
  unsigned short* H3s = (unsigned short*)(ws + H3OFF);
  int* bar = (int*)(ws + H3OFF + (hist ? 201 : 2) * SLOT);

  conv_wih1p<<<dim3(4096),    192, 0, stream>>>(W_ih1, Wih1p);
  conv_whh1 <<<dim3(4, 4096), 256, 0, stream>>>(W_hh1, Whh1);
  wf_gemm   <<<dim3(4, 4096), 256, 0, stream>>>(W_ih1, W_dec, Wf);
  conv_w23  <<<dim3(8, 4096), 256, 0, stream>>>(W_ih2, W_hh2, W2);
  conv_w23  <<<dim3(8, 4096), 256, 0, stream>>>(W_ih3, W_hh3, W3);
  conv_wd   <<<dim3(4, 176),  256, 0, stream>>>(W_dec, Wd);
  bias_all  <<<dim3(49),      256, 0, stream>>>(b_ih1, b_hh1, W_ih1, b_dec,
                                                b_ih2, b_hh2, b_ih3, b_hh3,
                                                B1gt, B1sc, B2, B3, Bd);
  // zero H1[2], H2[2] + h3 slot0 (+slot1 in ping mode)
  init_state<<<dim3(3072), 256, 0, stream>>>(Hb, (hist ? 5 : 6) * BB * HH, bar);

  if (hist)
    persistent_lstm<true><<<dim3(256), dim3(1024), 0, stream>>>(
        Wih1p, Whh1, Wf, W2, W3, Wd, B1gt, B1sc, B2, B3, Bd,
        Hb, H3s, seq, out, gtp, condp, bar);
  else
    persistent_lstm<false><<<dim3(256), dim3(1024), 0, stream>>>(
        Wih1p, Whh1, Wf, W2, W3, Wd, B1gt, B1sc, B2, B3, Bd,
        Hb, H3s, seq, out, gtp, condp, bar);
}